// Round 11
// baseline (351.175 us; speedup 1.0000x reference)
//
#include <hip/hip_runtime.h>
#include <hip/hip_bf16.h>

#define IN_DIM 128
#define HID 24
#define OUT_DIM 4096
#define NB 16384
#define KMOV 256

#define TR_BLOCKS 384            // 384*256 == OUT_DIM*HID exactly
#define MLP_BLOCKS (NB / 8)      // 8 rows per block

typedef float f32x4 __attribute__((ext_vector_type(4)));  // clang vector: OK for nontemporal builtins

// ---------------- Kernel 1: fused W3-transpose + 2-layer MLP -----------------
// Blocks [0,384): transpose W3 [24,4096] -> W3T [4096,24]
// Blocks [384, 384+2048): h2 = relu(relu(x@W1+b1)@W2+b2), 8 rows/block
__global__ __launch_bounds__(256) void kprep(const float* __restrict__ x,
                                             const float* __restrict__ W1,
                                             const float* __restrict__ b1,
                                             const float* __restrict__ W2,
                                             const float* __restrict__ b2,
                                             const float* __restrict__ W3,
                                             float* __restrict__ W3T,
                                             float* __restrict__ h2out) {
    __shared__ float W1s[IN_DIM * HID];   // 12 KB
    __shared__ float W2s[HID * HID];
    __shared__ float b1s[HID], b2s[HID];
    __shared__ float xs[8][IN_DIM];       // 4 KB

    int bid = blockIdx.x;
    int t = threadIdx.x;

    if (bid < TR_BLOCKS) {                // transpose path (whole block)
        int i = bid * 256 + t;
        int c = i / HID;
        int k = i - c * HID;
        W3T[i] = W3[k * OUT_DIM + c];
        return;
    }

    // ---- MLP path ----
    for (int i = t; i < IN_DIM * HID; i += 256) W1s[i] = W1[i];
    for (int i = t; i < HID * HID; i += 256)    W2s[i] = W2[i];
    if (t < HID) { b1s[t] = b1[t]; b2s[t] = b2[t]; }
    int rbase = (bid - TR_BLOCKS) * 8;
    for (int i = t; i < 8 * IN_DIM; i += 256)
        xs[i >> 7][i & 127] = x[(size_t)rbase * IN_DIM + i];
    __syncthreads();

    int g = t >> 5;        // row group 0..7
    int j = t & 31;        // lane within group
    int r = rbase + g;

    float h1 = 0.f;
    if (j < HID) {
        h1 = b1s[j];
        #pragma unroll 8
        for (int i = 0; i < IN_DIM; i++) h1 += xs[g][i] * W1s[i * HID + j];
        h1 = fmaxf(h1, 0.f);
    }
    float h2 = (j < HID) ? b2s[j] : 0.f;
    #pragma unroll
    for (int k = 0; k < HID; k++) {
        float hk = __shfl(h1, k, 32);   // broadcast within 32-lane group
        if (j < HID) h2 += hk * W2s[k * HID + j];
    }
    if (j < HID) {
        h2 = fmaxf(h2, 0.f);
        h2out[(size_t)r * HID + j] = h2;
    }
}

// ---------------- Kernel 2: masked softmax, delta-assembled row --------------
// One block per row. Key restructure vs R9:
//  * probs[] holds DELTAS (e - base_e), filled with zeros — the fill has no
//    data dependency, so it overlaps the gather/dot/max phase.
//  * final value computed at write time: (delta + base_e) * inv.
//  * dedup is FREE: summing the assembled array counts each unique move once
//    (duplicates write bitwise-identical deltas to the same slot), so the
//    readback pass IS the denominator reduction — claimed[] eliminated.
//  * gathers issue before barrier A (only need c); L2 latency hidden.
//  * 4 barriers (was 5); nontemporal stores (row never re-read from L2).
__global__ __launch_bounds__(256) void kmain2(const int* __restrict__ moves,
                                              const float* __restrict__ b3,
                                              const float* __restrict__ W3T,
                                              const float* __restrict__ h2all,
                                              float* __restrict__ out) {
    __shared__ __align__(16) float probs[OUT_DIM];   // 16 KB (deltas)
    __shared__ float h2s[HID];
    __shared__ float red[8];

    int r = blockIdx.x;
    int t = threadIdx.x;

    int c = moves[(size_t)r * KMOV + t];
    if (t < HID) h2s[t] = h2all[(size_t)r * HID + t];

    // issue gathers pre-barrier: only c needed; latency overlaps barrier+fill
    const float4* w = (const float4*)(W3T + c * HID);
    float4 a0 = w[0], a1 = w[1], a2 = w[2], a3 = w[3], a4 = w[4], a5 = w[5];
    float bc = b3[c];
    __syncthreads();   // A: h2s visible (gathers still in flight)

    // zero-fill deltas (no data deps — overlaps gather latency & dot)
    float4* p4 = (float4*)probs;
    float4 z = make_float4(0.f, 0.f, 0.f, 0.f);
    #pragma unroll
    for (int i = 0; i < 4; i++) p4[t + i * 256] = z;

    // dot24 -> logit
    float acc = bc;
    acc += a0.x*h2s[0] + a0.y*h2s[1] + a0.z*h2s[2]  + a0.w*h2s[3];
    acc += a1.x*h2s[4] + a1.y*h2s[5] + a1.z*h2s[6]  + a1.w*h2s[7];
    acc += a2.x*h2s[8] + a2.y*h2s[9] + a2.z*h2s[10] + a2.w*h2s[11];
    acc += a3.x*h2s[12]+ a3.y*h2s[13]+ a3.z*h2s[14] + a3.w*h2s[15];
    acc += a4.x*h2s[16]+ a4.y*h2s[17]+ a4.z*h2s[18] + a4.w*h2s[19];
    acc += a5.x*h2s[20]+ a5.y*h2s[21]+ a5.z*h2s[22] + a5.w*h2s[23];

    // block max of logits
    float m = acc;
    #pragma unroll
    for (int off = 32; off > 0; off >>= 1) m = fmaxf(m, __shfl_xor(m, off, 64));
    int wid = t >> 6;
    if ((t & 63) == 0) red[wid] = m;
    __syncthreads();   // B: orders zero-fill AND red[0..3]
    float mm = fmaxf(fmaxf(fmaxf(red[0], red[1]), fmaxf(red[2], red[3])), 0.f);

    float base_e = __expf(-mm);                  // uniform per block
    float em     = __expf(acc - mm) - base_e;    // delta (duplicates identical)

    probs[c] = em;     // scatter on top of zeros (ordered by B)
    __syncthreads();   // C: scatter visible

    // readback (doubles as dedup-sum: each unique move slot counted once)
    float4 v0 = p4[t], v1 = p4[t + 256], v2 = p4[t + 512], v3 = p4[t + 768];
    float s = (v0.x + v0.y + v0.z + v0.w) + (v1.x + v1.y + v1.z + v1.w)
            + (v2.x + v2.y + v2.z + v2.w) + (v3.x + v3.y + v3.z + v3.w);
    #pragma unroll
    for (int off = 32; off > 0; off >>= 1) s += __shfl_xor(s, off, 64);
    if ((t & 63) == 0) red[4 + wid] = s;
    __syncthreads();   // D
    float denom = (float)OUT_DIM * base_e + (red[4] + red[5] + red[6] + red[7]);
    float inv = 1.0f / denom;

    // write: (delta + base_e) * inv ; nontemporal (stream, skip L2 allocate)
    f32x4* out4 = (f32x4*)(out + (size_t)r * OUT_DIM);
    f32x4 r0, r1, r2, r3;
    r0.x=(v0.x+base_e)*inv; r0.y=(v0.y+base_e)*inv; r0.z=(v0.z+base_e)*inv; r0.w=(v0.w+base_e)*inv;
    r1.x=(v1.x+base_e)*inv; r1.y=(v1.y+base_e)*inv; r1.z=(v1.z+base_e)*inv; r1.w=(v1.w+base_e)*inv;
    r2.x=(v2.x+base_e)*inv; r2.y=(v2.y+base_e)*inv; r2.z=(v2.z+base_e)*inv; r2.w=(v2.w+base_e)*inv;
    r3.x=(v3.x+base_e)*inv; r3.y=(v3.y+base_e)*inv; r3.z=(v3.w+base_e)*inv; r3.w=(v3.w+base_e)*inv;
    // fix typo above: r3.z must use v3.z
    r3.z=(v3.z+base_e)*inv;
    __builtin_nontemporal_store(r0, &out4[t]);
    __builtin_nontemporal_store(r1, &out4[t + 256]);
    __builtin_nontemporal_store(r2, &out4[t + 512]);
    __builtin_nontemporal_store(r3, &out4[t + 768]);
}

extern "C" void kernel_launch(void* const* d_in, const int* in_sizes, int n_in,
                              void* d_out, int out_size, void* d_ws, size_t ws_size,
                              hipStream_t stream) {
    const float* x     = (const float*)d_in[0];
    const int*   moves = (const int*)  d_in[1];
    const float* W1    = (const float*)d_in[2];
    const float* b1    = (const float*)d_in[3];
    const float* W2    = (const float*)d_in[4];
    const float* b2    = (const float*)d_in[5];
    const float* W3    = (const float*)d_in[6];
    const float* b3    = (const float*)d_in[7];
    float* out = (float*)d_out;

    char* ws = (char*)d_ws;
    float* W3T = (float*)ws;                              // 384 KB
    float* h2  = (float*)(ws + OUT_DIM * HID * 4);        // 1.5 MB

    kprep<<<TR_BLOCKS + MLP_BLOCKS, 256, 0, stream>>>(x, W1, b1, W2, b2, W3, W3T, h2);
    kmain2<<<NB, 256, 0, stream>>>(moves, b3, W3T, h2, out);
}

// Round 12
// 351.097 us; speedup vs baseline: 1.0002x; 1.0002x over previous
//
#include <hip/hip_runtime.h>
#include <hip/hip_bf16.h>

#define IN_DIM 128
#define HID 24
#define OUT_DIM 4096
#define NB 16384
#define KMOV 256

#define TR_BLOCKS 384            // 384*256 == OUT_DIM*HID exactly
#define MLP_BLOCKS (NB / 8)      // 8 rows per block

// ---------------- Kernel 1: fused W3-transpose + 2-layer MLP -----------------
// Blocks [0,384): transpose W3 [24,4096] -> W3T [4096,24]
// Blocks [384, 384+2048): h2 = relu(relu(x@W1+b1)@W2+b2), 8 rows/block
__global__ __launch_bounds__(256) void kprep(const float* __restrict__ x,
                                             const float* __restrict__ W1,
                                             const float* __restrict__ b1,
                                             const float* __restrict__ W2,
                                             const float* __restrict__ b2,
                                             const float* __restrict__ W3,
                                             float* __restrict__ W3T,
                                             float* __restrict__ h2out) {
    __shared__ float W1s[IN_DIM * HID];   // 12 KB
    __shared__ float W2s[HID * HID];
    __shared__ float b1s[HID], b2s[HID];
    __shared__ float xs[8][IN_DIM];       // 4 KB

    int bid = blockIdx.x;
    int t = threadIdx.x;

    if (bid < TR_BLOCKS) {                // transpose path (whole block)
        int i = bid * 256 + t;
        int c = i / HID;
        int k = i - c * HID;
        W3T[i] = W3[k * OUT_DIM + c];
        return;
    }

    // ---- MLP path ----
    for (int i = t; i < IN_DIM * HID; i += 256) W1s[i] = W1[i];
    for (int i = t; i < HID * HID; i += 256)    W2s[i] = W2[i];
    if (t < HID) { b1s[t] = b1[t]; b2s[t] = b2[t]; }
    int rbase = (bid - TR_BLOCKS) * 8;
    for (int i = t; i < 8 * IN_DIM; i += 256)
        xs[i >> 7][i & 127] = x[(size_t)rbase * IN_DIM + i];
    __syncthreads();

    int g = t >> 5;        // row group 0..7
    int j = t & 31;        // lane within group
    int r = rbase + g;

    float h1 = 0.f;
    if (j < HID) {
        h1 = b1s[j];
        #pragma unroll 8
        for (int i = 0; i < IN_DIM; i++) h1 += xs[g][i] * W1s[i * HID + j];
        h1 = fmaxf(h1, 0.f);
    }
    float h2 = (j < HID) ? b2s[j] : 0.f;
    #pragma unroll
    for (int k = 0; k < HID; k++) {
        float hk = __shfl(h1, k, 32);   // broadcast within 32-lane group
        if (j < HID) h2 += hk * W2s[k * HID + j];
    }
    if (j < HID) {
        h2 = fmaxf(h2, 0.f);
        h2out[(size_t)r * HID + j] = h2;
    }
}

// ---------------- Kernel 2: masked softmax, delta-assembled row --------------
// R11 structure, but PLAIN L2-allocating stores (A/B isolating the nt flag):
//  * probs[] holds DELTAS (e - base_e), zero-filled (no data dependency ->
//    fill overlaps gather/dot/max).
//  * final value computed at write time: (delta + base_e) * inv.
//  * dedup free: readback-sum counts each unique move slot once (duplicates
//    wrote bitwise-identical deltas). claimed[] eliminated; 4 barriers.
__global__ __launch_bounds__(256) void kmain2(const int* __restrict__ moves,
                                              const float* __restrict__ b3,
                                              const float* __restrict__ W3T,
                                              const float* __restrict__ h2all,
                                              float* __restrict__ out) {
    __shared__ __align__(16) float probs[OUT_DIM];   // 16 KB (deltas)
    __shared__ float h2s[HID];
    __shared__ float red[8];

    int r = blockIdx.x;
    int t = threadIdx.x;

    int c = moves[(size_t)r * KMOV + t];
    if (t < HID) h2s[t] = h2all[(size_t)r * HID + t];

    // issue gathers pre-barrier: only c needed; latency overlaps barrier+fill
    const float4* w = (const float4*)(W3T + c * HID);
    float4 a0 = w[0], a1 = w[1], a2 = w[2], a3 = w[3], a4 = w[4], a5 = w[5];
    float bc = b3[c];
    __syncthreads();   // A: h2s visible (gathers still in flight)

    // zero-fill deltas (no data deps — overlaps gather latency & dot)
    float4* p4 = (float4*)probs;
    float4 z = make_float4(0.f, 0.f, 0.f, 0.f);
    #pragma unroll
    for (int i = 0; i < 4; i++) p4[t + i * 256] = z;

    // dot24 -> logit
    float acc = bc;
    acc += a0.x*h2s[0] + a0.y*h2s[1] + a0.z*h2s[2]  + a0.w*h2s[3];
    acc += a1.x*h2s[4] + a1.y*h2s[5] + a1.z*h2s[6]  + a1.w*h2s[7];
    acc += a2.x*h2s[8] + a2.y*h2s[9] + a2.z*h2s[10] + a2.w*h2s[11];
    acc += a3.x*h2s[12]+ a3.y*h2s[13]+ a3.z*h2s[14] + a3.w*h2s[15];
    acc += a4.x*h2s[16]+ a4.y*h2s[17]+ a4.z*h2s[18] + a4.w*h2s[19];
    acc += a5.x*h2s[20]+ a5.y*h2s[21]+ a5.z*h2s[22] + a5.w*h2s[23];

    // block max of logits
    float m = acc;
    #pragma unroll
    for (int off = 32; off > 0; off >>= 1) m = fmaxf(m, __shfl_xor(m, off, 64));
    int wid = t >> 6;
    if ((t & 63) == 0) red[wid] = m;
    __syncthreads();   // B: orders zero-fill AND red[0..3]
    float mm = fmaxf(fmaxf(fmaxf(red[0], red[1]), fmaxf(red[2], red[3])), 0.f);

    float base_e = __expf(-mm);                  // uniform per block
    float em     = __expf(acc - mm) - base_e;    // delta (duplicates identical)

    probs[c] = em;     // scatter on top of zeros (ordered by B)
    __syncthreads();   // C: scatter visible

    // readback (doubles as dedup-sum: each unique move slot counted once)
    float4 v0 = p4[t], v1 = p4[t + 256], v2 = p4[t + 512], v3 = p4[t + 768];
    float s = (v0.x + v0.y + v0.z + v0.w) + (v1.x + v1.y + v1.z + v1.w)
            + (v2.x + v2.y + v2.z + v2.w) + (v3.x + v3.y + v3.z + v3.w);
    #pragma unroll
    for (int off = 32; off > 0; off >>= 1) s += __shfl_xor(s, off, 64);
    if ((t & 63) == 0) red[4 + wid] = s;
    __syncthreads();   // D
    float denom = (float)OUT_DIM * base_e + (red[4] + red[5] + red[6] + red[7]);
    float inv = 1.0f / denom;

    // write: (delta + base_e) * inv ; plain stores (L2 write-coalescing path)
    float4* out4 = (float4*)(out + (size_t)r * OUT_DIM);
    float4 r0, r1, r2, r3;
    r0.x=(v0.x+base_e)*inv; r0.y=(v0.y+base_e)*inv; r0.z=(v0.z+base_e)*inv; r0.w=(v0.w+base_e)*inv;
    r1.x=(v1.x+base_e)*inv; r1.y=(v1.y+base_e)*inv; r1.z=(v1.z+base_e)*inv; r1.w=(v1.w+base_e)*inv;
    r2.x=(v2.x+base_e)*inv; r2.y=(v2.y+base_e)*inv; r2.z=(v2.z+base_e)*inv; r2.w=(v2.w+base_e)*inv;
    r3.x=(v3.x+base_e)*inv; r3.y=(v3.y+base_e)*inv; r3.z=(v3.z+base_e)*inv; r3.w=(v3.w+base_e)*inv;
    out4[t]       = r0;
    out4[t + 256] = r1;
    out4[t + 512] = r2;
    out4[t + 768] = r3;
}

extern "C" void kernel_launch(void* const* d_in, const int* in_sizes, int n_in,
                              void* d_out, int out_size, void* d_ws, size_t ws_size,
                              hipStream_t stream) {
    const float* x     = (const float*)d_in[0];
    const int*   moves = (const int*)  d_in[1];
    const float* W1    = (const float*)d_in[2];
    const float* b1    = (const float*)d_in[3];
    const float* W2    = (const float*)d_in[4];
    const float* b2    = (const float*)d_in[5];
    const float* W3    = (const float*)d_in[6];
    const float* b3    = (const float*)d_in[7];
    float* out = (float*)d_out;

    char* ws = (char*)d_ws;
    float* W3T = (float*)ws;                              // 384 KB
    float* h2  = (float*)(ws + OUT_DIM * HID * 4);        // 1.5 MB

    kprep<<<TR_BLOCKS + MLP_BLOCKS, 256, 0, stream>>>(x, W1, b1, W2, b2, W3, W3T, h2);
    kmain2<<<NB, 256, 0, stream>>>(moves, b3, W3T, h2, out);
}

// Round 14
// 329.652 us; speedup vs baseline: 1.0653x; 1.0651x over previous
//
#include <hip/hip_runtime.h>
#include <hip/hip_bf16.h>

#define IN_DIM 128
#define HID 24
#define OUT_DIM 4096
#define NB 16384
#define KMOV 256

#define TR_BLOCKS 384            // 384*256 == OUT_DIM*HID exactly
#define MLP_BLOCKS (NB / 8)      // 8 rows per block

// ---------------- Kernel 1: fused W3-transpose + 2-layer MLP -----------------
// Blocks [0,384): transpose W3 [24,4096] -> W3T [4096,24]
// Blocks [384, 384+2048): h2 = relu(relu(x@W1+b1)@W2+b2), 8 rows/block
__global__ __launch_bounds__(256) void kprep(const float* __restrict__ x,
                                             const float* __restrict__ W1,
                                             const float* __restrict__ b1,
                                             const float* __restrict__ W2,
                                             const float* __restrict__ b2,
                                             const float* __restrict__ W3,
                                             float* __restrict__ W3T,
                                             float* __restrict__ h2out) {
    __shared__ float W1s[IN_DIM * HID];   // 12 KB
    __shared__ float W2s[HID * HID];
    __shared__ float b1s[HID], b2s[HID];
    __shared__ float xs[8][IN_DIM];       // 4 KB

    int bid = blockIdx.x;
    int t = threadIdx.x;

    if (bid < TR_BLOCKS) {                // transpose path (whole block)
        int i = bid * 256 + t;
        int c = i / HID;
        int k = i - c * HID;
        W3T[i] = W3[k * OUT_DIM + c];
        return;
    }

    // ---- MLP path ----
    for (int i = t; i < IN_DIM * HID; i += 256) W1s[i] = W1[i];
    for (int i = t; i < HID * HID; i += 256)    W2s[i] = W2[i];
    if (t < HID) { b1s[t] = b1[t]; b2s[t] = b2[t]; }
    int rbase = (bid - TR_BLOCKS) * 8;
    for (int i = t; i < 8 * IN_DIM; i += 256)
        xs[i >> 7][i & 127] = x[(size_t)rbase * IN_DIM + i];
    __syncthreads();

    int g = t >> 5;        // row group 0..7
    int j = t & 31;        // lane within group
    int r = rbase + g;

    float h1 = 0.f;
    if (j < HID) {
        h1 = b1s[j];
        #pragma unroll 8
        for (int i = 0; i < IN_DIM; i++) h1 += xs[g][i] * W1s[i * HID + j];
        h1 = fmaxf(h1, 0.f);
    }
    float h2 = (j < HID) ? b2s[j] : 0.f;
    #pragma unroll
    for (int k = 0; k < HID; k++) {
        float hk = __shfl(h1, k, 32);   // broadcast within 32-lane group
        if (j < HID) h2 += hk * W2s[k * HID + j];
    }
    if (j < HID) {
        h2 = fmaxf(h2, 0.f);
        h2out[(size_t)r * HID + j] = h2;
    }
}

// ---------------- Kernel 2: masked softmax, LDS-assembled row ----------------
// R9 structure (measured best, 330 µs) — reverted from the R11/12 delta
// experiment (+21 µs: denominator-from-LDS-readback serialized the store
// phase). Here the denominator is a register-local shuffle reduce (claimed[]
// dedup), so the final LDS readback pipelines directly into global stores.
// LDS aliasing: claimed[] (phases 1-2) overlays probs[] (phase 3), separated
// by the post-sum barrier.
__global__ __launch_bounds__(256) void kmain2(const int* __restrict__ moves,
                                              const float* __restrict__ b3,
                                              const float* __restrict__ W3T,
                                              const float* __restrict__ h2all,
                                              float* __restrict__ out) {
    __shared__ __align__(16) float probs[OUT_DIM];   // 16 KB union
    __shared__ float h2s[HID];
    __shared__ float red[8];
    unsigned char* claimed = (unsigned char*)probs;  // [0,4096) alias, phases 1-2

    int r = blockIdx.x;
    int t = threadIdx.x;

    int c = moves[(size_t)r * KMOV + t];
    if (t < HID) h2s[t] = h2all[(size_t)r * HID + t];
    __syncthreads();   // h2s visible

    // ---- gather W3T column (24 contiguous floats), dot24 -> logit ----
    const float4* w = (const float4*)(W3T + c * HID);
    float4 a0 = w[0], a1 = w[1], a2 = w[2], a3 = w[3], a4 = w[4], a5 = w[5];
    float acc = b3[c];
    acc += a0.x*h2s[0] + a0.y*h2s[1] + a0.z*h2s[2]  + a0.w*h2s[3];
    acc += a1.x*h2s[4] + a1.y*h2s[5] + a1.z*h2s[6]  + a1.w*h2s[7];
    acc += a2.x*h2s[8] + a2.y*h2s[9] + a2.z*h2s[10] + a2.w*h2s[11];
    acc += a3.x*h2s[12]+ a3.y*h2s[13]+ a3.z*h2s[14] + a3.w*h2s[15];
    acc += a4.x*h2s[16]+ a4.y*h2s[17]+ a4.z*h2s[18] + a4.w*h2s[19];
    acc += a5.x*h2s[20]+ a5.y*h2s[21]+ a5.z*h2s[22] + a5.w*h2s[23];

    // claim slot c (any winner; duplicates produce bitwise-identical e)
    claimed[c] = (unsigned char)t;

    // ---- block max of logits ----
    float m = acc;
    #pragma unroll
    for (int off = 32; off > 0; off >>= 1) m = fmaxf(m, __shfl_xor(m, off, 64));
    int wid = t >> 6;
    if ((t & 63) == 0) red[wid] = m;
    __syncthreads();   // orders claimed[] writes AND red[0..3]
    float mm = fmaxf(fmaxf(fmaxf(red[0], red[1]), fmaxf(red[2], red[3])), 0.f);

    float e      = __expf(acc - mm);   // native v_exp_f32
    float base_e = __expf(-mm);

    // ---- denominator with duplicates counted once (register-local) ----
    float contrib = (claimed[c] == (unsigned char)t) ? (e - base_e) : 0.f;
    float s = contrib;
    #pragma unroll
    for (int off = 32; off > 0; off >>= 1) s += __shfl_xor(s, off, 64);
    if ((t & 63) == 0) red[4 + wid] = s;
    __syncthreads();   // claimed reads complete; probs may overlay from here
    float denom = (float)OUT_DIM * base_e + (red[4] + red[5] + red[6] + red[7]);
    float inv = 1.0f / denom;
    float oc  = base_e * inv;
    float pm  = e * inv;

    // ---- assemble full row in LDS ----
    float4* p4 = (float4*)probs;
    float4 ocv = make_float4(oc, oc, oc, oc);
    #pragma unroll
    for (int i = 0; i < 4; i++) p4[t + i * 256] = ocv;
    __syncthreads();
    probs[c] = pm;     // in-LDS scatter (duplicates write identical bits)
    __syncthreads();

    // ---- single streaming write pass: full 64B lines only ----
    float4* out4 = (float4*)(out + (size_t)r * OUT_DIM);
    #pragma unroll
    for (int i = 0; i < 4; i++) out4[t + i * 256] = p4[t + i * 256];
}

extern "C" void kernel_launch(void* const* d_in, const int* in_sizes, int n_in,
                              void* d_out, int out_size, void* d_ws, size_t ws_size,
                              hipStream_t stream) {
    const float* x     = (const float*)d_in[0];
    const int*   moves = (const int*)  d_in[1];
    const float* W1    = (const float*)d_in[2];
    const float* b1    = (const float*)d_in[3];
    const float* W2    = (const float*)d_in[4];
    const float* b2    = (const float*)d_in[5];
    const float* W3    = (const float*)d_in[6];
    const float* b3    = (const float*)d_in[7];
    float* out = (float*)d_out;

    char* ws = (char*)d_ws;
    float* W3T = (float*)ws;                              // 384 KB
    float* h2  = (float*)(ws + OUT_DIM * HID * 4);        // 1.5 MB

    kprep<<<TR_BLOCKS + MLP_BLOCKS, 256, 0, stream>>>(x, W1, b1, W2, b2, W3, W3T, h2);
    kmain2<<<NB, 256, 0, stream>>>(moves, b3, W3T, h2, out);
}